// Round 3
// baseline (132.797 us; speedup 1.0000x reference)
//
#include <hip/hip_runtime.h>

// SSIM (window=3, stride=3, pad=1) on (16,3,512,512) fp32 -> scalar mean.
// V3: back to the R1-proven two-kernel skeleton (no LDS staging — the R2 LDS
// version tripped the post-timing divergence check for reasons not yet
// explained; R1's structure passed the full harness). Bottleneck attack:
// 4 outputs per thread via 16B-ALIGNED float4 loads. Windows of outputs
// ox=4k..4k+3 need floats [12k-1, 12k+10]; aligned float4 slots q=3k-1..3k+2
// cover [12k-4, 12k+12) and 16*(3k-1) is 16B-aligned. 24 vmem instr per
// 4 outputs vs 18 per 1 output in R1 (3x fewer vmem instructions).

#define HW       512
#define PLANE_SZ (HW * HW)
#define OHW      171                      // (512 + 2 - 3)/3 + 1
#define NPLANE   48                       // 16 batch * 3 channels
#define NOUT     (NPLANE * OHW * OHW)     // 1,403,568
#define OX4      43                       // ceil(171/4) output-col groups
#define NGROUPS  (NPLANE * OHW * OX4)     // 353,064 (one group = up to 4 outputs)
#define TPB      256
#define NBLK     ((NGROUPS + TPB - 1) / TPB)   // 1380

typedef float f4 __attribute__((ext_vector_type(4)));

__global__ __launch_bounds__(TPB) void ssim_main(
    const float* __restrict__ img1, const float* __restrict__ img2,
    const float* __restrict__ win, float* __restrict__ partial) {
  float w[9];
#pragma unroll
  for (int i = 0; i < 9; ++i) w[i] = win[i];   // identical for all channels

  const float C1 = 0.01f * 0.01f;
  const float C2 = 0.03f * 0.03f;

  float acc = 0.0f;
  const int idx = blockIdx.x * TPB + threadIdx.x;
  if (idx < NGROUPS) {
    int ox4 = idx % OX4;
    int t   = idx / OX4;
    int oy  = t % OHW;
    int p   = t / OHW;                       // plane 0..47
    const float* a = img1 + (size_t)p * PLANE_SZ;
    const float* b = img2 + (size_t)p * PLANE_SZ;
    const int iy0 = 3 * oy - 1;              // top window row (pad=1)
    const int q0  = 3 * ox4 - 1;             // first aligned float4 slot

    float s1[4]  = {0.f, 0.f, 0.f, 0.f};
    float s2[4]  = {0.f, 0.f, 0.f, 0.f};
    float s11[4] = {0.f, 0.f, 0.f, 0.f};
    float s22[4] = {0.f, 0.f, 0.f, 0.f};
    float s12[4] = {0.f, 0.f, 0.f, 0.f};

#pragma unroll
    for (int r = 0; r < 3; ++r) {
      const int iy = iy0 + r;                // -1 only at oy==0; <=511 always
      float xa[16], xb[16];
      if (iy >= 0) {
        const f4* pa = (const f4*)(a + (size_t)iy * HW);
        const f4* pb = (const f4*)(b + (size_t)iy * HW);
#pragma unroll
        for (int tq = 0; tq < 4; ++tq) {
          const int q = q0 + tq;             // -1 (left pad) .. 128 (right edge)
          f4 va = {0.f, 0.f, 0.f, 0.f};
          f4 vb = {0.f, 0.f, 0.f, 0.f};
          if (q >= 0 && q < HW / 4) { va = pa[q]; vb = pb[q]; }
#pragma unroll
          for (int e = 0; e < 4; ++e) { xa[4 * tq + e] = va[e]; xb[4 * tq + e] = vb[e]; }
        }
      } else {
#pragma unroll
        for (int e = 0; e < 16; ++e) { xa[e] = 0.f; xb[e] = 0.f; }
      }
      // local col c maps to global float col 12*ox4 - 4 + c.
      // output j (ox=4*ox4+j) uses cols 3j+3 .. 3j+5.
#pragma unroll
      for (int j = 0; j < 4; ++j) {
#pragma unroll
        for (int kx = 0; kx < 3; ++kx) {
          const float wv = w[3 * r + kx];
          const float x = xa[3 * j + 3 + kx];
          const float y = xb[3 * j + 3 + kx];
          s1[j]  += wv * x;
          s2[j]  += wv * y;
          s11[j] += wv * x * x;
          s22[j] += wv * y * y;
          s12[j] += wv * x * y;
        }
      }
    }

    const int oxb = 4 * ox4;
#pragma unroll
    for (int j = 0; j < 4; ++j) {
      if (oxb + j < OHW) {
        const float mu11 = s1[j] * s1[j];
        const float mu22 = s2[j] * s2[j];
        const float mu12 = s1[j] * s2[j];
        const float sg1  = s11[j] - mu11;
        const float sg2  = s22[j] - mu22;
        const float sg12 = s12[j] - mu12;
        const float num = (2.0f * mu12 + C1) * (2.0f * sg12 + C2);
        const float den = (mu11 + mu22 + C1) * (sg1 + sg2 + C2);
        acc += num / den;
      }
    }
  }

  // wave(64) shuffle reduce -> LDS -> one write per block (R1-proven pattern)
#pragma unroll
  for (int off = 32; off > 0; off >>= 1) acc += __shfl_down(acc, off, 64);
  __shared__ float wsum[TPB / 64];
  const int lane = threadIdx.x & 63, wid = threadIdx.x >> 6;
  if (lane == 0) wsum[wid] = acc;
  __syncthreads();
  if (threadIdx.x == 0) {
    float s = 0.f;
#pragma unroll
    for (int i = 0; i < TPB / 64; ++i) s += wsum[i];
    partial[blockIdx.x] = s;   // every block writes its slot: no init needed
  }
}

__global__ __launch_bounds__(256) void ssim_final(
    const float* __restrict__ partial, float* __restrict__ out) {
  double acc = 0.0;
  for (int i = threadIdx.x; i < NBLK; i += 256) acc += (double)partial[i];
#pragma unroll
  for (int off = 32; off > 0; off >>= 1) acc += __shfl_down(acc, off, 64);
  __shared__ double wsum[4];
  const int lane = threadIdx.x & 63, wid = threadIdx.x >> 6;
  if (lane == 0) wsum[wid] = acc;
  __syncthreads();
  if (threadIdx.x == 0) {
    double s = 0.0;
#pragma unroll
    for (int i = 0; i < 4; ++i) s += wsum[i];
    out[0] = (float)(s / (double)NOUT);
  }
}

extern "C" void kernel_launch(void* const* d_in, const int* in_sizes, int n_in,
                              void* d_out, int out_size, void* d_ws, size_t ws_size,
                              hipStream_t stream) {
  const float* img1 = (const float*)d_in[0];
  const float* img2 = (const float*)d_in[1];
  const float* win  = (const float*)d_in[2];
  float* partial = (float*)d_ws;   // NBLK floats
  float* out = (float*)d_out;

  ssim_main<<<NBLK, TPB, 0, stream>>>(img1, img2, win, partial);
  ssim_final<<<1, 256, 0, stream>>>(partial, out);
}

// Round 4
// 130.030 us; speedup vs baseline: 1.0213x; 1.0213x over previous
//
#include <hip/hip_runtime.h>

// SSIM (window=3, stride=3, pad=1) on (16,3,512,512) fp32 -> scalar mean.
// V4: branchless clustered loads. R3 diagnosis: loads buried in per-row /
// per-slot branches => compiler serialized (VGPR=60, ~2 loads in flight/CU,
// 1.4 TB/s, VALUBusy 12%, latency-bound). Here all 24 float4 loads per
// thread are unconditional (clamped addresses), issued as one cluster, and
// pad handling is arithmetic: top pad via zeroed effective weights, left pad
// via zeroing element 3 of slot 0. Right-edge clamp only feeds the discarded
// j=3 output at ox4==42.

#define HW       512
#define PLANE_SZ (HW * HW)
#define OHW      171                      // (512 + 2 - 3)/3 + 1
#define NPLANE   48                       // 16 batch * 3 channels
#define NOUT     (NPLANE * OHW * OHW)     // 1,403,568
#define OX4      43                       // ceil(171/4) output-col groups
#define NGROUPS  (NPLANE * OHW * OX4)     // 353,064
#define TPB      256
#define NBLK     ((NGROUPS + TPB - 1) / TPB)   // 1380

typedef float f4 __attribute__((ext_vector_type(4)));

__global__ __launch_bounds__(TPB) void ssim_main(
    const float* __restrict__ img1, const float* __restrict__ img2,
    const float* __restrict__ win, float* __restrict__ partial) {
  float w[9];
#pragma unroll
  for (int i = 0; i < 9; ++i) w[i] = win[i];   // identical for all channels

  const float C1 = 0.01f * 0.01f;
  const float C2 = 0.03f * 0.03f;

  float acc = 0.0f;
  const int idx = blockIdx.x * TPB + threadIdx.x;
  if (idx < NGROUPS) {
    const int ox4 = idx % OX4;
    const int t   = idx / OX4;
    const int oy  = t % OHW;
    const int p   = t / OHW;                 // plane 0..47
    const float* a = img1 + (size_t)p * PLANE_SZ;
    const float* b = img2 + (size_t)p * PLANE_SZ;
    const int iy0 = 3 * oy - 1;              // top window row (pad=1)
    const int q0  = 3 * ox4 - 1;             // first aligned float4 slot

    const float topf  = (iy0 >= 0) ? 1.0f : 0.0f;  // row 0 validity (oy==0 pad)
    const float leftf = (q0  >= 0) ? 1.0f : 0.0f;  // slot 0 elem 3 validity

    // ---- load phase: 24 unconditional float4 loads, clamped addresses ----
    f4 va[12], vb[12];
#pragma unroll
    for (int r = 0; r < 3; ++r) {
      const int iy  = iy0 + r;
      const int iyc = iy < 0 ? 0 : iy;       // iy <= 511 always
      const float* ra = a + (size_t)iyc * HW;
      const float* rb = b + (size_t)iyc * HW;
#pragma unroll
      for (int tq = 0; tq < 4; ++tq) {
        int q = q0 + tq;                     // -1 .. 128
        q = q < 0 ? 0 : (q > 127 ? 127 : q);
        va[r * 4 + tq] = *(const f4*)(ra + 4 * q);
        vb[r * 4 + tq] = *(const f4*)(rb + 4 * q);
      }
    }

    // ---- pad cancellation (arithmetic, no branches) ----
    // left pad: local col 3 (elem 3 of slot 0) is global col -1 when ox4==0
#pragma unroll
    for (int r = 0; r < 3; ++r) {
      va[r * 4][3] *= leftf;
      vb[r * 4][3] *= leftf;
    }
    // top pad: zero row-0 weights when oy==0 (clamped row-0 data cancels)
    float wr[9];
#pragma unroll
    for (int kx = 0; kx < 3; ++kx) wr[kx] = w[kx] * topf;
#pragma unroll
    for (int i = 3; i < 9; ++i) wr[i] = w[i];

    // ---- compute phase ----
    float s1[4]  = {0.f, 0.f, 0.f, 0.f};
    float s2[4]  = {0.f, 0.f, 0.f, 0.f};
    float s11[4] = {0.f, 0.f, 0.f, 0.f};
    float s22[4] = {0.f, 0.f, 0.f, 0.f};
    float s12[4] = {0.f, 0.f, 0.f, 0.f};
#pragma unroll
    for (int r = 0; r < 3; ++r) {
#pragma unroll
      for (int j = 0; j < 4; ++j) {
#pragma unroll
        for (int kx = 0; kx < 3; ++kx) {
          const int c = 3 * j + 3 + kx;      // local col 3..14
          const float wv = wr[3 * r + kx];
          const float x = va[r * 4 + (c >> 2)][c & 3];
          const float y = vb[r * 4 + (c >> 2)][c & 3];
          const float t1 = wv * x;
          const float t2 = wv * y;
          s1[j]  += t1;
          s2[j]  += t2;
          s11[j] = fmaf(t1, x, s11[j]);
          s22[j] = fmaf(t2, y, s22[j]);
          s12[j] = fmaf(t1, y, s12[j]);
        }
      }
    }

    const int oxb = 4 * ox4;
#pragma unroll
    for (int j = 0; j < 4; ++j) {
      if (oxb + j < OHW) {
        const float mu11 = s1[j] * s1[j];
        const float mu22 = s2[j] * s2[j];
        const float mu12 = s1[j] * s2[j];
        const float sg1  = s11[j] - mu11;
        const float sg2  = s22[j] - mu22;
        const float sg12 = s12[j] - mu12;
        const float num = (2.0f * mu12 + C1) * (2.0f * sg12 + C2);
        const float den = (mu11 + mu22 + C1) * (sg1 + sg2 + C2);
        acc += num / den;
      }
    }
  }

  // wave(64) shuffle reduce -> LDS -> one write per block (proven pattern)
#pragma unroll
  for (int off = 32; off > 0; off >>= 1) acc += __shfl_down(acc, off, 64);
  __shared__ float wsum[TPB / 64];
  const int lane = threadIdx.x & 63, wid = threadIdx.x >> 6;
  if (lane == 0) wsum[wid] = acc;
  __syncthreads();
  if (threadIdx.x == 0) {
    float s = 0.f;
#pragma unroll
    for (int i = 0; i < TPB / 64; ++i) s += wsum[i];
    partial[blockIdx.x] = s;   // every block writes its slot: no init needed
  }
}

__global__ __launch_bounds__(256) void ssim_final(
    const float* __restrict__ partial, float* __restrict__ out) {
  double acc = 0.0;
  for (int i = threadIdx.x; i < NBLK; i += 256) acc += (double)partial[i];
#pragma unroll
  for (int off = 32; off > 0; off >>= 1) acc += __shfl_down(acc, off, 64);
  __shared__ double wsum[4];
  const int lane = threadIdx.x & 63, wid = threadIdx.x >> 6;
  if (lane == 0) wsum[wid] = acc;
  __syncthreads();
  if (threadIdx.x == 0) {
    double s = 0.0;
#pragma unroll
    for (int i = 0; i < 4; ++i) s += wsum[i];
    out[0] = (float)(s / (double)NOUT);
  }
}

extern "C" void kernel_launch(void* const* d_in, const int* in_sizes, int n_in,
                              void* d_out, int out_size, void* d_ws, size_t ws_size,
                              hipStream_t stream) {
  const float* img1 = (const float*)d_in[0];
  const float* img2 = (const float*)d_in[1];
  const float* win  = (const float*)d_in[2];
  float* partial = (float*)d_ws;   // NBLK floats
  float* out = (float*)d_out;

  ssim_main<<<NBLK, TPB, 0, stream>>>(img1, img2, win, partial);
  ssim_final<<<1, 256, 0, stream>>>(partial, out);
}

// Round 5
// 119.946 us; speedup vs baseline: 1.1071x; 1.0841x over previous
//
#include <hip/hip_runtime.h>

// SSIM (window=3, stride=3, pad=1) on (16,3,512,512) fp32 -> scalar mean.
// V5: wave-cooperative, PERFECTLY COALESCED loads. Diagnosis across R1/R3/R4:
// all variants with 12/48B lane strides plateau at 40-46us (~1 lane-dword/cy/CU
// gather path, ~2.5 TB/s ceiling); contiguous 16B/lane waves hit 6.3+ TB/s.
// Here: one wave per (plane, output-row). Lane i loads f4 slots i and i+64 of
// 3 input rows x 2 images (12 x 1KB contiguous wave-loads). Window is
// separable (w = g outer g): collapse rows with wy, scale cols by wx, bin each
// f4's 4 cols into its 2 output bins via mask arithmetic (split set by
// c0 mod 3), merge boundaries with one shfl_up per quantity. Each of the 171
// bins/row is owned by exactly one lane. Top pad: zero wy[0] + clamp row.

#define HW       512
#define PLANE_SZ (HW * HW)
#define OHW      171                    // (512 + 2 - 3)/3 + 1
#define NPLANE   48                     // 16 batch * 3 channels
#define NOUT     (NPLANE * OHW * OHW)   // 1,403,568
#define NTASK    (NPLANE * OHW)         // 8208 wave-tasks
#define TPB      256
#define WPB      4                      // waves per block
#define NBLK     (NTASK / WPB)          // 2052 (exact)

typedef float f4 __attribute__((ext_vector_type(4)));

__device__ __forceinline__ float ssim_val(float s1, float s2, float s11,
                                          float s22, float s12) {
  const float C1 = 1e-4f, C2 = 9e-4f;
  const float m11 = s1 * s1, m22 = s2 * s2, m12 = s1 * s2;
  const float sg1 = s11 - m11, sg2 = s22 - m22, sg12 = s12 - m12;
  return ((2.0f * m12 + C1) * (2.0f * sg12 + C2)) /
         ((m11 + m22 + C1) * (sg1 + sg2 + C2));
}

__global__ __launch_bounds__(TPB) void ssim_main(
    const float* __restrict__ img1, const float* __restrict__ img2,
    const float* __restrict__ win, float* __restrict__ partial) {
  const int lane  = threadIdx.x & 63;
  const int wv    = threadIdx.x >> 6;
  const int task  = blockIdx.x * WPB + wv;     // < 8208 always (grid exact)
  const int plane = task / OHW;
  const int oy    = task - plane * OHW;

  // Separable weights: w[3r+c] = wy[r]*wx[c] (window = outer(g,g), sum(g)=1).
  float wy[3], wx[3];
#pragma unroll
  for (int k = 0; k < 3; ++k) {
    wy[k] = win[3 * k] + win[3 * k + 1] + win[3 * k + 2];
    wx[k] = win[k] + win[k + 3] + win[k + 6];
  }
  const int r0 = 3 * oy - 1;                   // top window row (pad=1)
  float wyv[3];
  wyv[0] = (r0 >= 0) ? wy[0] : 0.0f;           // oy==0: zero-weight top row
  wyv[1] = wy[1];
  wyv[2] = wy[2];
  const int rr0 = (r0 < 0) ? 0 : r0;

  const float* a = img1 + (size_t)plane * PLANE_SZ;
  const float* b = img2 + (size_t)plane * PLANE_SZ;

  // ---- 12 fully-coalesced float4 wave-loads (16B lane stride) ----
  f4 xa[3][2], xb[3][2];
#pragma unroll
  for (int k = 0; k < 3; ++k) {
    const int r = (k == 0) ? rr0 : (r0 + k);   // rows 3oy..3oy+1 always valid
    const f4* ra = (const f4*)(a + (size_t)r * HW);
    const f4* rb = (const f4*)(b + (size_t)r * HW);
    xa[k][0] = ra[lane];      xa[k][1] = ra[lane + 64];
    xb[k][0] = rb[lane];      xb[k][1] = rb[lane + 64];
  }

  float acc = 0.0f;
  float fwd[5];                                // chunk-A right partials (seam)

#pragma unroll
  for (int c = 0; c < 2; ++c) {
    // chunk start col c0 = 256*c + 4*lane; m = c0 % 3 (256 % 3 == 1)
    const int m = (lane + c) % 3;

    // ---- row collapse with wy ----
    float P1[4]  = {0.f, 0.f, 0.f, 0.f};
    float P2[4]  = {0.f, 0.f, 0.f, 0.f};
    float P11[4] = {0.f, 0.f, 0.f, 0.f};
    float P22[4] = {0.f, 0.f, 0.f, 0.f};
    float P12[4] = {0.f, 0.f, 0.f, 0.f};
#pragma unroll
    for (int k = 0; k < 3; ++k) {
      const float wyk = wyv[k];
#pragma unroll
      for (int j = 0; j < 4; ++j) {
        const float x = xa[k][c][j];
        const float y = xb[k][c][j];
        const float u = wyk * x;
        const float v = wyk * y;
        P1[j] += u;
        P2[j] += v;
        P11[j] = fmaf(u, x, P11[j]);
        P22[j] = fmaf(v, y, P22[j]);
        P12[j] = fmaf(u, y, P12[j]);
      }
    }

    // ---- column weights: col c0+j has wx index (c0+j+1)%3 = (m+j+1)%3 ----
    float wxl[4];
#pragma unroll
    for (int j = 0; j < 4; ++j) {
      const int ix = (m + j + 1) % 3;
      wxl[j] = (ix == 0) ? wx[0] : ((ix == 1) ? wx[1] : wx[2]);
    }

    // ---- bin split: left-mask by m: m==0 ->{1,1,0,0}, 1->{1,0,0,0}, 2->{1,1,1,0}
    const float aL = (m != 1) ? 1.0f : 0.0f;
    const float bL = (m == 2) ? 1.0f : 0.0f;
    float L[5], R[5];
    {
      float t0, t1, t2, t3, full, left;
#define BIN(Q, P)                                              \
      t0 = wxl[0] * P[0]; t1 = wxl[1] * P[1];                  \
      t2 = wxl[2] * P[2]; t3 = wxl[3] * P[3];                  \
      full = (t0 + t1) + (t2 + t3);                            \
      left = fmaf(bL, t2, fmaf(aL, t1, t0));                   \
      L[Q] = left; R[Q] = full - left;
      BIN(0, P1) BIN(1, P2) BIN(2, P11) BIN(3, P22) BIN(4, P12)
#undef BIN
    }
    if (c == 0) {
#pragma unroll
      for (int q = 0; q < 5; ++q) fwd[q] = R[q];
    }

    // ---- merge: L-bin takes previous lane's R when incomplete (m != 2) ----
    const float allow =
        (m != 2 && !(c == 0 && lane == 0)) ? 1.0f : 0.0f;  // lane0 A: left pad
#pragma unroll
    for (int q = 0; q < 5; ++q) {
      float up = __shfl_up(R[q], 1, 64);
      if (c == 1) {
        const float seam = __shfl(fwd[q], 63, 64);  // chunk-A lane63 R
        up = (lane == 0) ? seam : up;
      }
      L[q] = fmaf(allow, up, L[q]);
    }

    // ---- finalize: L-bin always owned; R-bin owned iff m == 1 ----
    const float mR = (m == 1) ? 1.0f : 0.0f;
    acc += ssim_val(L[0], L[1], L[2], L[3], L[4]);
    acc += mR * ssim_val(R[0], R[1], R[2], R[3], R[4]);
  }

  // wave(64) shuffle reduce -> LDS -> one write per block (proven pattern)
#pragma unroll
  for (int off = 32; off > 0; off >>= 1) acc += __shfl_down(acc, off, 64);
  __shared__ float wsum[TPB / 64];
  if (lane == 0) wsum[wv] = acc;
  __syncthreads();
  if (threadIdx.x == 0) {
    float s = 0.f;
#pragma unroll
    for (int i = 0; i < TPB / 64; ++i) s += wsum[i];
    partial[blockIdx.x] = s;   // every block writes its slot: no init needed
  }
}

__global__ __launch_bounds__(256) void ssim_final(
    const float* __restrict__ partial, float* __restrict__ out) {
  double acc = 0.0;
  for (int i = threadIdx.x; i < NBLK; i += 256) acc += (double)partial[i];
#pragma unroll
  for (int off = 32; off > 0; off >>= 1) acc += __shfl_down(acc, off, 64);
  __shared__ double wsum[4];
  const int lane = threadIdx.x & 63, wid = threadIdx.x >> 6;
  if (lane == 0) wsum[wid] = acc;
  __syncthreads();
  if (threadIdx.x == 0) {
    double s = 0.0;
#pragma unroll
    for (int i = 0; i < 4; ++i) s += wsum[i];
    out[0] = (float)(s / (double)NOUT);
  }
}

extern "C" void kernel_launch(void* const* d_in, const int* in_sizes, int n_in,
                              void* d_out, int out_size, void* d_ws, size_t ws_size,
                              hipStream_t stream) {
  const float* img1 = (const float*)d_in[0];
  const float* img2 = (const float*)d_in[1];
  const float* win  = (const float*)d_in[2];
  float* partial = (float*)d_ws;   // NBLK floats
  float* out = (float*)d_out;

  ssim_main<<<NBLK, TPB, 0, stream>>>(img1, img2, win, partial);
  ssim_final<<<1, 256, 0, stream>>>(partial, out);
}